// Round 16
// baseline (1440.487 us; speedup 1.0000x reference)
//
#include <hip/hip_runtime.h>
#include <math.h>

#define B_ 128
#define N_ 197
#define C_ 768
#define H_ 12
#define D_ 64
#define KEEP_ 138
#define COMP_ 58
#define NOUT_ 139
#define HID_ 3072

typedef __attribute__((ext_vector_type(8))) short bf16x8;
typedef __attribute__((ext_vector_type(8))) _Float16 f16x8;
typedef __attribute__((ext_vector_type(4))) float f32x4;
typedef unsigned short us;

__device__ inline us f2bf(float f) {
    unsigned u = __float_as_uint(f);
    unsigned r = (u + 0x7FFFu + ((u >> 16) & 1u)) >> 16;
    return (us)r;
}
__device__ inline float bf2f(us h) { return __uint_as_float(((unsigned)h) << 16); }
__device__ inline void gload_lds16(const void* g, void* l) {
    __builtin_amdgcn_global_load_lds((const __attribute__((address_space(1))) void*)g,
                                     (__attribute__((address_space(3))) void*)l, 16, 0, 0);
}
__device__ inline void split3(float v, us& h1, us& h2, us& h3) {
    h1 = f2bf(v);
    float r1 = v - bf2f(h1);
    h2 = f2bf(r1);
    h3 = f2bf(r1 - bf2f(h2));
}
// fp16 split-2 with scaled residual plane (x ~= h1 + h2*2^-12).
__device__ inline void split2h(float v, us& h1, us& h2) {
    float av = fabsf(v);
    float v1 = (av < 6.103515625e-05f) ? 0.f : v;
    _Float16 a = (_Float16)v1;
    float r = (v - (float)a) * 4096.0f;
    _Float16 b = (_Float16)r;
    h1 = *reinterpret_cast<us*>(&a);
    h2 = *reinterpret_cast<us*>(&b);
}

// Fast GELU (exact-erf form) via Abramowitz-Stegun 7.1.26 (max abs err 1.5e-7);
// bf16-rounded output is bit-identical vs libm erff.
__device__ inline float fast_gelu(float v) {
    float x = v * 0.70710678118654752f;
    float ax = fabsf(x);
    float t = __frcp_rn(__fmaf_rn(0.3275911f, ax, 1.0f));
    float p = __fmaf_rn(1.061405429f, t, -1.453152027f);
    p = __fmaf_rn(p, t, 1.421413741f);
    p = __fmaf_rn(p, t, -0.284496736f);
    p = __fmaf_rn(p, t, 0.254829592f);
    p = p * t;
    float e = __expf(-x * x);
    float erfa = __fmaf_rn(-p, e, 1.0f);
    float er = (x < 0.f) ? -erfa : erfa;
    return 0.5f * v * (1.0f + er);
}

// XCD-aware bijective grid swizzle (T1, m204 formula). Pure index permutation ->
// bitwise-identical results. Round-14 verified (-41 us via qkv/proj L2 locality).
__device__ inline void xcd_swizzle(int GX, int GY, int& bx, int& by) {
    int nwg = GX * GY;
    int orig = by * GX + bx;
    int q = nwg >> 3, r = nwg & 7;
    int xcd = orig & 7, idx = orig >> 3;
    int wgid = (xcd < r ? xcd * (q + 1) : r * (q + 1) + (xcd - r) * q) + idx;
    bx = wgid % GX;
    by = wgid / GX;
}

// counted-vmcnt barrier discipline (T4): never drain vmcnt to 0 in the main loop.
#define WAITV(n) asm volatile("s_waitcnt vmcnt(" #n ")" ::: "memory")
#define RBAR __builtin_amdgcn_s_barrier()

// ---------------- LayerNorm1 -> 2-plane scaled fp16 split ----------------
__global__ __launch_bounds__(256) void ln_split2h_kernel(const float* __restrict__ x,
                                                         const float* __restrict__ w,
                                                         const float* __restrict__ bias,
                                                         us* __restrict__ y1,
                                                         us* __restrict__ y2) {
    int row = blockIdx.x;
    const float* xr = x + (size_t)row * C_;
    int tid = threadIdx.x;
    float v[3];
    float s = 0.f, sq = 0.f;
#pragma unroll
    for (int i = 0; i < 3; i++) {
        v[i] = xr[tid + i * 256];
        s += v[i];
        sq += v[i] * v[i];
    }
    __shared__ float s1[256], s2[256];
    s1[tid] = s; s2[tid] = sq;
    __syncthreads();
    for (int o = 128; o > 0; o >>= 1) {
        if (tid < o) { s1[tid] += s1[tid + o]; s2[tid] += s2[tid + o]; }
        __syncthreads();
    }
    float mean = s1[0] * (1.0f / C_);
    float var = s2[0] * (1.0f / C_) - mean * mean;
    float rstd = rsqrtf(var + 1e-5f);
#pragma unroll
    for (int i = 0; i < 3; i++) {
        int c = tid + i * 256;
        float y = (v[i] - mean) * rstd * w[c] + bias[c];
        us h1, h2;
        split2h(y, h1, h2);
        size_t o = (size_t)row * C_ + c;
        y1[o] = h1; y2[o] = h2;
    }
}

// ---------------- LayerNorm -> bf16 output (MLP) ----------------
__global__ __launch_bounds__(256) void ln2bf_kernel(const float* __restrict__ x,
                                                    const float* __restrict__ w,
                                                    const float* __restrict__ bias,
                                                    us* __restrict__ y) {
    int row = blockIdx.x;
    const float* xr = x + (size_t)row * C_;
    us* yr = y + (size_t)row * C_;
    int tid = threadIdx.x;
    float v[3];
    float s = 0.f, sq = 0.f;
#pragma unroll
    for (int i = 0; i < 3; i++) {
        v[i] = xr[tid + i * 256];
        s += v[i];
        sq += v[i] * v[i];
    }
    __shared__ float s1[256], s2[256];
    s1[tid] = s; s2[tid] = sq;
    __syncthreads();
    for (int o = 128; o > 0; o >>= 1) {
        if (tid < o) { s1[tid] += s1[tid + o]; s2[tid] += s2[tid + o]; }
        __syncthreads();
    }
    float mean = s1[0] * (1.0f / C_);
    float var = s2[0] * (1.0f / C_) - mean * mean;
    float rstd = rsqrtf(var + 1e-5f);
#pragma unroll
    for (int i = 0; i < 3; i++) {
        int c = tid + i * 256;
        yr[c] = f2bf((v[i] - mean) * rstd * w[c] + bias[c]);
    }
}

// ---------------- weight transpose: in[K][N] fp32 -> out[N][K] bf16 (MLP) ----------------
__global__ __launch_bounds__(256) void wtrans_kernel(const float* __restrict__ in,
                                                     us* __restrict__ out,
                                                     int K, int N) {
    __shared__ float T[32][33];
    int n0 = blockIdx.x * 32, k0 = blockIdx.y * 32;
    int tx = threadIdx.x & 31, ty = threadIdx.x >> 5;
    for (int i = 0; i < 32; i += 8)
        T[ty + i][tx] = in[(size_t)(k0 + ty + i) * N + n0 + tx];
    __syncthreads();
    for (int i = 0; i < 32; i += 8)
        out[(size_t)(n0 + ty + i) * K + k0 + tx] = f2bf(T[tx][ty + i]);
}

// ---------------- weight transpose split2h: in[K][N] fp32 -> 2x [N][K] fp16 ----------------
__global__ __launch_bounds__(256) void wtrans_split2h_kernel(const float* __restrict__ in,
                                                             us* __restrict__ o1,
                                                             us* __restrict__ o2,
                                                             int K, int N) {
    __shared__ float T[32][33];
    int n0 = blockIdx.x * 32, k0 = blockIdx.y * 32;
    int tx = threadIdx.x & 31, ty = threadIdx.x >> 5;
    for (int i = 0; i < 32; i += 8)
        T[ty + i][tx] = in[(size_t)(k0 + ty + i) * N + n0 + tx];
    __syncthreads();
    for (int i = 0; i < 32; i += 8) {
        us h1, h2;
        split2h(T[tx][ty + i], h1, h2);
        size_t o = (size_t)(n0 + ty + i) * K + k0 + tx;
        o1[o] = h1; o2[o] = h2;
    }
}

// ---------------- split-2 scaled-fp16 MFMA GEMM (front), 3 products ----------------
// Round-6 verified: 2 blocks/CU, BK=64, zero bank conflicts. Round-14: + XCD swizzle.
template <bool BIAS, bool RES>
__global__ __launch_bounds__(256, 2) void bgemm3h_kernel(const us* __restrict__ A1,
                                                         const us* __restrict__ A2,
                                                         const us* __restrict__ B1,
                                                         const us* __restrict__ B2,
                                                         const float* __restrict__ bias,
                                                         const float* __restrict__ res,
                                                         float* __restrict__ Cm,
                                                         int M, int N, int K) {
    __shared__ short As[2][128 * 64];
    __shared__ short Bs[2][128 * 64];
    int tid = threadIdx.x;
    int lane = tid & 63, wid = tid >> 6;
    int wr = wid >> 1, wc = wid & 1;
    int lr = lane & 15, g = lane >> 4;
    int bx = blockIdx.x, by = blockIdx.y;
    xcd_swizzle(gridDim.x, gridDim.y, bx, by);
    int brow = by * 128, bcol = bx * 128;

    f32x4 acc0[4][4] = {};
    f32x4 acc1[4][4] = {};

    for (int k0 = 0; k0 < K; k0 += 64) {
#pragma unroll
        for (int v = 0; v < 4; v++) {
            int rowb = v * 32 + wid * 8;           // wave-uniform 8-row group
            int r = rowb + (lane >> 3);
            int slot = lane & 7;
            int chunk = slot ^ (r & 7);
            int garow = brow + r; if (garow >= M) garow = M - 1;
            int gbrow = bcol + r;
            gload_lds16(A1 + (size_t)garow * K + k0 + chunk * 8, &As[0][rowb * 64]);
            gload_lds16(A2 + (size_t)garow * K + k0 + chunk * 8, &As[1][rowb * 64]);
            gload_lds16(B1 + (size_t)gbrow * K + k0 + chunk * 8, &Bs[0][rowb * 64]);
            gload_lds16(B2 + (size_t)gbrow * K + k0 + chunk * 8, &Bs[1][rowb * 64]);
        }
        __syncthreads();
#pragma unroll
        for (int kk = 0; kk < 2; kk++) {
            f16x8 af[2][4], bfr[2][4];
#pragma unroll
            for (int fi = 0; fi < 4; fi++) {
                int ra = wr * 64 + fi * 16 + lr;
                int sla = (kk * 4 + g) ^ (ra & 7);
                int rb = wc * 64 + fi * 16 + lr;
                int slb = (kk * 4 + g) ^ (rb & 7);
#pragma unroll
                for (int s = 0; s < 2; s++) {
                    af[s][fi] = *reinterpret_cast<const f16x8*>(&As[s][ra * 64 + sla * 8]);
                    bfr[s][fi] = *reinterpret_cast<const f16x8*>(&Bs[s][rb * 64 + slb * 8]);
                }
            }
#pragma unroll
            for (int fi = 0; fi < 4; fi++)
#pragma unroll
                for (int fj = 0; fj < 4; fj++) {
                    acc0[fi][fj] = __builtin_amdgcn_mfma_f32_16x16x32_f16(af[0][fi], bfr[0][fj], acc0[fi][fj], 0, 0, 0);
                    acc1[fi][fj] = __builtin_amdgcn_mfma_f32_16x16x32_f16(af[0][fi], bfr[1][fj], acc1[fi][fj], 0, 0, 0);
                    acc1[fi][fj] = __builtin_amdgcn_mfma_f32_16x16x32_f16(af[1][fi], bfr[0][fj], acc1[fi][fj], 0, 0, 0);
                }
        }
        __syncthreads();
    }
#pragma unroll
    for (int fi = 0; fi < 4; fi++) {
#pragma unroll
        for (int fj = 0; fj < 4; fj++) {
            int col = bcol + wc * 64 + fj * 16 + lr;
            float bv = BIAS ? bias[col] : 0.f;
#pragma unroll
            for (int i = 0; i < 4; i++) {
                int r = brow + wr * 64 + fi * 16 + g * 4 + i;
                if (r < M) {
                    float vv = acc0[fi][fj][i] + acc1[fi][fj][i] * (1.0f / 4096.0f) + bv;
                    if (RES) vv += res[(size_t)r * N + col];
                    Cm[(size_t)r * N + col] = vv;
                }
            }
        }
    }
}

// ---------------- bf16 MFMA GEMM (MLP): 256x256 tile, dbuf + counted vmcnt ----------------
// Round-15: BM=BN=256, BK=64, 512 threads (8 waves 2x4; wave = 128x64 out,
// acc[8][4] = 128 AGPR). Per wave per K-step: 64 MFMA vs 24 ds_read_b128 --
// double the payload density of the 128^2 shape -- and the 1-deep dbuf prefetch
// (round-4-verified stage->WAITV(8)->barrier->compute discipline) now ages a
// full ~640 compute-cycles, hiding HBM latency even at 1 block/CU (the failure
// mode of big tiles on short-compute shapes). Same (r&7) XOR swizzle (rows are
// 64 shorts, unchanged). LDS 2x(32+32) = 128 KB. Per-output K-ascending MFMA
// chain identical to round-11 -> bitwise-identical results.
template <bool GELU_, bool OUTBF, bool RES>
__global__ __launch_bounds__(512, 2) void bgemm_kernel(const us* __restrict__ A,
                                                       const us* __restrict__ Bt,
                                                       const float* __restrict__ bias,
                                                       const float* __restrict__ res,
                                                       void* __restrict__ Cout,
                                                       int M, int N, int K) {
    __shared__ short As[2][256 * 64];
    __shared__ short Bs[2][256 * 64];
    int tid = threadIdx.x;
    int lane = tid & 63, wid = tid >> 6;          // wid 0..7
    int wr = wid >> 2, wc = wid & 3;              // 2 x 4 waves; wave tile 128x64
    int lr = lane & 15, g = lane >> 4;
    int bx = blockIdx.x, by = blockIdx.y;
    xcd_swizzle(gridDim.x, gridDim.y, bx, by);
    int brow = by * 256, bcol = bx * 256;

    f32x4 acc[8][4] = {};

    auto stage = [&](int buf, int k0) {
        // 256 rows of A + 256 rows of B, 8-row wave-uniform groups, 8 loads/thread.
#pragma unroll
        for (int v = 0; v < 4; v++) {
            int rowb = v * 64 + wid * 8;
            int r = rowb + (lane >> 3);
            int chunk = (lane & 7) ^ (r & 7);
            int garow = brow + r; if (garow >= M) garow = M - 1;
            gload_lds16(A + (size_t)garow * K + k0 + chunk * 8, &As[buf][rowb * 64]);
            gload_lds16(Bt + (size_t)(bcol + r) * K + k0 + chunk * 8, &Bs[buf][rowb * 64]);
        }
    };
    auto compute = [&](int buf) {
#pragma unroll
        for (int kk = 0; kk < 2; kk++) {
            bf16x8 bfr[4];
#pragma unroll
            for (int fj = 0; fj < 4; fj++) {
                int rb = wc * 64 + fj * 16 + lr;
                int slb = (kk * 4 + g) ^ (rb & 7);
                bfr[fj] = *reinterpret_cast<const bf16x8*>(&Bs[buf][rb * 64 + slb * 8]);
            }
#pragma unroll
            for (int fi = 0; fi < 8; fi++) {
                int ra = wr * 128 + fi * 16 + lr;
                int sla = (kk * 4 + g) ^ (ra & 7);
                bf16x8 af = *reinterpret_cast<const bf16x8*>(&As[buf][ra * 64 + sla * 8]);
#pragma unroll
                for (int fj = 0; fj < 4; fj++)
                    acc[fi][fj] = __builtin_amdgcn_mfma_f32_16x16x32_bf16(af, bfr[fj], acc[fi][fj], 0, 0, 0);
            }
        }
    };

    stage(0, 0);
    int cur = 0;
    for (int k0 = 0; k0 < K; k0 += 64) {
        if (k0 + 64 < K) {
            stage(cur ^ 1, k0 + 64);
            WAITV(8);
        } else {
            WAITV(0);
        }
        RBAR;
        compute(cur);
        RBAR;
        cur ^= 1;
    }
#pragma unroll
    for (int fi = 0; fi < 8; fi++) {
#pragma unroll
        for (int fj = 0; fj < 4; fj++) {
            int col = bcol + wc * 64 + fj * 16 + lr;
            float bv = bias[col];
#pragma unroll
            for (int i = 0; i < 4; i++) {
                int r = brow + wr * 128 + fi * 16 + g * 4 + i;
                if (r < M) {
                    float vv = acc[fi][fj][i] + bv;
                    if (GELU_) vv = fast_gelu(vv);
                    if (OUTBF) {
                        ((us*)Cout)[(size_t)r * N + col] = f2bf(vv);
                    } else {
                        if (RES) vv += res[(size_t)r * N + col];
                        ((float*)Cout)[(size_t)r * N + col] = vv;
                    }
                }
            }
        }
    }
}

// ---------------- attention v12: scaled-fp16 split-2 QK^T + padded Pscr (round-12 verified) ----------------
__global__ __launch_bounds__(512, 1) void attn12_kernel(const float* __restrict__ qkv,
                                                        us* __restrict__ ao1,
                                                        us* __restrict__ ao2,
                                                        float* __restrict__ attn0,
                                                        int b0) {
    int hh = blockIdx.x, b = blockIdx.y;
    int tid = threadIdx.x, lane = tid & 63, wv = tid >> 6;
    int lr = lane & 15, g = lane >> 4;
    __shared__ short Ks[2][208 * 64];
    __shared__ short Vt[2][64 * 224];
    __shared__ unsigned Pscr[8][16 * 36];
    const size_t base = (size_t)b * N_ * 3 * C_ + (size_t)hh * D_;

    for (int i = tid; i < 208 * 8; i += 512) {
        int k = i >> 3, oct = i & 7;
        int d0 = (oct ^ (k & 7)) * 8;
        float tv[8];
        if (k < N_) {
            const float4* kp = reinterpret_cast<const float4*>(qkv + base + (size_t)k * 3 * C_ + C_ + d0);
            float4 aa = kp[0], bb = kp[1];
            tv[0] = aa.x; tv[1] = aa.y; tv[2] = aa.z; tv[3] = aa.w;
            tv[4] = bb.x; tv[5] = bb.y; tv[6] = bb.z; tv[7] = bb.w;
        } else {
#pragma unroll
            for (int e = 0; e < 8; e++) tv[e] = 0.f;
        }
        bf16x8 h1v, h2v;
#pragma unroll
        for (int e = 0; e < 8; e++) {
            us ha, hb;
            split2h(tv[e], ha, hb);
            h1v[e] = (short)ha; h2v[e] = (short)hb;
        }
        int di = k * 64 + oct * 8;
        *reinterpret_cast<bf16x8*>(&Ks[0][di]) = h1v;
        *reinterpret_cast<bf16x8*>(&Ks[1][di]) = h2v;
    }
    {
        int d = tid & 63, jb = tid >> 6;
        for (int it = 0; it < 28; it++) {
            int k = it * 8 + jb;
            float vv = (k < N_) ? qkv[base + (size_t)k * 3 * C_ + 2 * C_ + d] : 0.f;
            us p1 = f2bf(vv);
            us p2 = f2bf(vv - bf2f(p1));
            int idx = d * 224 + (((k >> 3) ^ (d & 3)) * 8) + (k & 7);
            Vt[0][idx] = (short)p1;
            Vt[1][idx] = (short)p2;
        }
    }
    __syncthreads();

#pragma unroll
    for (int chunk = 0; chunk < 2; chunk++) {
        int qbase = chunk * 128 + wv * 16;
        f16x8 qf1[2], qf2[2];
        int qrow = qbase + lr;
#pragma unroll
        for (int kk = 0; kk < 2; kk++) {
            float qv[8];
            if (qrow < N_) {
                const float4* qp = reinterpret_cast<const float4*>(qkv + base + (size_t)qrow * 3 * C_ + kk * 32 + g * 8);
                float4 aa = qp[0], bb = qp[1];
                qv[0] = aa.x; qv[1] = aa.y; qv[2] = aa.z; qv[3] = aa.w;
                qv[4] = bb.x; qv[5] = bb.y; qv[6] = bb.z; qv[7] = bb.w;
            } else {
#pragma unroll
                for (int e = 0; e < 8; e++) qv[e] = 0.f;
            }
#pragma unroll
            for (int e = 0; e < 8; e++) {
                us ha, hb;
                split2h(qv[e], ha, hb);
                qf1[kk][e] = *reinterpret_cast<_Float16*>(&ha);
                qf2[kk][e] = *reinterpret_cast<_Float16*>(&hb);
            }
        }
        f32x4 sacc[13] = {};
        f32x4 sacc1[13] = {};
#pragma unroll
        for (int kt = 0; kt < 13; kt++) {
#pragma unroll
            for (int kk = 0; kk < 2; kk++) {
                int row = kt * 16 + lr;
                int sl = ((kk * 4 + g) ^ (row & 7)) * 8;
                const f16x8 b1 = *reinterpret_cast<const f16x8*>(&Ks[0][row * 64 + sl]);
                const f16x8 b2 = *reinterpret_cast<const f16x8*>(&Ks[1][row * 64 + sl]);
                sacc[kt]  = __builtin_amdgcn_mfma_f32_16x16x32_f16(qf1[kk], b1, sacc[kt], 0, 0, 0);
                sacc1[kt] = __builtin_amdgcn_mfma_f32_16x16x32_f16(qf1[kk], b2, sacc1[kt], 0, 0, 0);
                sacc1[kt] = __builtin_amdgcn_mfma_f32_16x16x32_f16(qf2[kk], b1, sacc1[kt], 0, 0, 0);
            }
        }
#pragma unroll
        for (int kt = 0; kt < 13; kt++)
#pragma unroll
            for (int i = 0; i < 4; i++)
                sacc[kt][i] += sacc1[kt][i] * (1.0f / 4096.0f);
#pragma unroll
        for (int i = 0; i < 4; i++) {
            float m = -1e30f;
#pragma unroll
            for (int kt = 0; kt < 13; kt++) {
                int k = kt * 16 + lr;
                float lgv = (k < N_) ? sacc[kt][i] * 0.125f : -1e30f;
                sacc[kt][i] = lgv;
                m = fmaxf(m, lgv);
            }
            m = fmaxf(m, __shfl_xor(m, 1, 64));
            m = fmaxf(m, __shfl_xor(m, 2, 64));
            m = fmaxf(m, __shfl_xor(m, 4, 64));
            m = fmaxf(m, __shfl_xor(m, 8, 64));
            float se = 0.f;
#pragma unroll
            for (int kt = 0; kt < 13; kt++) {
                int k = kt * 16 + lr;
                float e = (k < N_) ? expf(sacc[kt][i] - m) : 0.f;
                sacc[kt][i] = e;
                se += e;
            }
            se += __shfl_xor(se, 1, 64);
            se += __shfl_xor(se, 2, 64);
            se += __shfl_xor(se, 4, 64);
            se += __shfl_xor(se, 8, 64);
            float inv = 1.0f / se;
#pragma unroll
            for (int kt = 0; kt < 13; kt++) sacc[kt][i] *= inv;
        }
        if (chunk == 0 && wv == 0 && g == 0) {
#pragma unroll
            for (int kt = 0; kt < 13; kt++) {
                int k = kt * 16 + lr;
                if (k < N_) attn0[((size_t)(b0 + b) * H_ + hh) * N_ + k] = sacc[kt][0];
            }
        }
        f32x4 oacc[4] = {};
#pragma unroll
        for (int sect = 0; sect < 7; sect++) {
#pragma unroll
            for (int t = 0; t < 2; t++) {
                int kt = sect * 2 + t;
#pragma unroll
                for (int i = 0; i < 4; i++) {
                    float p = (kt < 13) ? sacc[kt][i] : 0.f;
                    us h1 = f2bf(p);
                    us h2 = f2bf(p - bf2f(h1));
                    Pscr[wv][(g * 4 + i) * 36 + t * 16 + lr] = (unsigned)h1 | ((unsigned)h2 << 16);
                }
            }
            uint4 u0 = *reinterpret_cast<const uint4*>(&Pscr[wv][lr * 36 + g * 8]);
            uint4 u1 = *reinterpret_cast<const uint4*>(&Pscr[wv][lr * 36 + g * 8 + 4]);
            unsigned uu[8] = {u0.x, u0.y, u0.z, u0.w, u1.x, u1.y, u1.z, u1.w};
            bf16x8 pa1, pa2;
#pragma unroll
            for (int e = 0; e < 8; e++) {
                pa1[e] = (short)(uu[e] & 0xffffu);
                pa2[e] = (short)(uu[e] >> 16);
            }
#pragma unroll
            for (int dt = 0; dt < 4; dt++) {
                int row = dt * 16 + lr;
                int cc = sect * 4 + g;
                int idx = row * 224 + ((cc ^ (row & 3)) * 8);
                const bf16x8 v1 = *reinterpret_cast<const bf16x8*>(&Vt[0][idx]);
                const bf16x8 v2 = *reinterpret_cast<const bf16x8*>(&Vt[1][idx]);
                oacc[dt] = __builtin_amdgcn_mfma_f32_16x16x32_bf16(pa1, v1, oacc[dt], 0, 0, 0);
                oacc[dt] = __builtin_amdgcn_mfma_f32_16x16x32_bf16(pa1, v2, oacc[dt], 0, 0, 0);
                oacc[dt] = __builtin_amdgcn_mfma_f32_16x16x32_bf16(pa2, v1, oacc[dt], 0, 0, 0);
            }
        }
#pragma unroll
        for (int dt = 0; dt < 4; dt++) {
#pragma unroll
            for (int i = 0; i < 4; i++) {
                int q = qbase + g * 4 + i;
                if (q < N_) {
                    int d = dt * 16 + lr;
                    size_t oi = ((size_t)(b * N_ + q)) * C_ + (size_t)hh * D_ + d;
                    us h1, h2;
                    split2h(oacc[dt][i], h1, h2);
                    ao1[oi] = h1; ao2[oi] = h2;
                }
            }
        }
    }
}

// ---------------- cls_attn ----------------
__global__ __launch_bounds__(256) void cls_kernel(const float* __restrict__ attn0,
                                                  float* __restrict__ cls) {
    int b = blockIdx.x, tid = threadIdx.x;
    if (tid < N_ - 1) {
        float s = 0.f;
        for (int hh = 0; hh < H_; hh++) s += attn0[((size_t)b * H_ + hh) * N_ + 1 + tid];
        cls[b * (N_ - 1) + tid] = s * (1.0f / H_);
    }
}

// ---------------- top-k + complement ----------------
__global__ __launch_bounds__(256) void topk_kernel(const float* __restrict__ cls,
                                                   int* __restrict__ idx,
                                                   int* __restrict__ cmp) {
    int b = blockIdx.x, tid = threadIdx.x;
    __shared__ float vals[196];
    __shared__ int rk[196];
    if (tid < 196) vals[tid] = cls[b * 196 + tid];
    __syncthreads();
    if (tid < 196) {
        float v = vals[tid];
        int r = 0;
        for (int j = 0; j < 196; j++) {
            float u = vals[j];
            r += (u > v) || (u == v && j < tid);
        }
        rk[tid] = r;
    }
    __syncthreads();
    if (tid < 196) {
        int r = rk[tid];
        if (r < KEEP_) {
            idx[b * KEEP_ + r] = tid;
        } else {
            int pos = 0;
            for (int j = 0; j < tid; j++) pos += (rk[j] >= KEEP_);
            cmp[b * COMP_ + pos] = tid;
        }
    }
}

// ---------------- reciprocal L2 norms ----------------
__global__ __launch_bounds__(256) void rnorm_kernel(const float* __restrict__ x1,
                                                    float* __restrict__ rn) {
    int i = blockIdx.x, b = blockIdx.y, tid = threadIdx.x;
    const float* xr = x1 + ((size_t)b * N_ + 1 + i) * C_;
    float sq = 0.f;
#pragma unroll
    for (int k = 0; k < 3; k++) {
        float v = xr[tid + k * 256];
        sq += v * v;
    }
    __shared__ float s2[256];
    s2[tid] = sq;
    __syncthreads();
    for (int o = 128; o > 0; o >>= 1) {
        if (tid < o) s2[tid] += s2[tid + o];
        __syncthreads();
    }
    if (tid == 0) rn[b * 196 + i] = rsqrtf(s2[0]);
}

// ---------------- distance v4: k-contiguous b128 LDS layout (round-13 verified) ----------------
__global__ __launch_bounds__(256, 3) void dist4_kernel(const float* __restrict__ x1,
                                                       const float* __restrict__ rn,
                                                       const int* __restrict__ idx,
                                                       const int* __restrict__ cmp,
                                                       int* __restrict__ node) {
    int b = blockIdx.x, half = blockIdx.y;
    int l0 = half * 29;
    int tid = threadIdx.x;
    __shared__ __align__(16) float As2[32][64];
    __shared__ __align__(16) float Bs2[138][64];
    __shared__ int cpl[29];
    __shared__ int til[KEEP_];
    __shared__ float rnt[KEEP_];
    if (tid < 29) cpl[tid] = cmp[b * COMP_ + l0 + tid];
    if (tid < KEEP_) {
        int t = idx[b * KEEP_ + tid];
        til[tid] = t;
        rnt[tid] = rn[b * 196 + t];
    }
    __syncthreads();
    int tr = tid >> 5, tc = tid & 31;
    int mb[5], mm[5];
#pragma unroll
    for (int j = 0; j < 5; j++) {
        int m = tc * 5 + j;
        int mc = (m < KEEP_) ? m : (KEEP_ - 1);
        mb[j] = mc * 64;
        mm[j] = mc & 15;
    }
    float acc[4][5] = {};
    for (int k0 = 0; k0 < C_; k0 += 64) {
        for (int ii = tid; ii < 29 * 16; ii += 256) {
            int l = ii >> 4, kc = ii & 15;
            *reinterpret_cast<float4*>(&As2[l][kc * 4]) =
                *reinterpret_cast<const float4*>(&x1[((size_t)b * N_ + 1 + cpl[l]) * C_ + k0 + kc * 4]);
        }
        for (int ii = tid; ii < KEEP_ * 16; ii += 256) {
            int m = ii >> 4, kc = ii & 15;
            *reinterpret_cast<float4*>(&Bs2[m][(kc ^ (m & 15)) * 4]) =
                *reinterpret_cast<const float4*>(&x1[((size_t)b * N_ + 1 + til[m]) * C_ + k0 + kc * 4]);
        }
        __syncthreads();
#pragma unroll 4
        for (int kc = 0; kc < 16; kc++) {
            float4 a4[4], b4[5];
#pragma unroll
            for (int i = 0; i < 4; i++)
                a4[i] = *reinterpret_cast<const float4*>(&As2[tr * 4 + i][kc * 4]);
#pragma unroll
            for (int j = 0; j < 5; j++)
                b4[j] = *reinterpret_cast<const float4*>(&Bs2[0][0] + mb[j] + ((kc ^ mm[j]) << 2));
#pragma unroll
            for (int i = 0; i < 4; i++)
#pragma unroll
                for (int j = 0; j < 5; j++) {
                    acc[i][j] += a4[i].x * b4[j].x;
                    acc[i][j] += a4[i].y * b4[j].y;
                    acc[i][j] += a4[i].z * b4[j].z;
                    acc[i][j] += a4[i].w * b4[j].w;
                }
        }
        __syncthreads();
    }
#pragma unroll
    for (int i = 0; i < 4; i++) {
        int ll = tr * 4 + i;
        if (ll < 29) {
            float best = -3.0e38f;
            int bm = 0x7fffffff;
#pragma unroll
            for (int j = 0; j < 5; j++) {
                int m = tc * 5 + j;
                if (m < KEEP_) {
                    float dv = acc[i][j] * rnt[m];
                    if (dv > best) { best = dv; bm = m; }
                }
            }
            for (int o = 1; o < 32; o <<= 1) {
                float ov = __shfl_xor(best, o, 64);
                int oi = __shfl_xor(bm, o, 64);
                if (ov > best || (ov == best && oi < bm)) { best = ov; bm = oi; }
            }
            if (tc == 0) node[b * COMP_ + l0 + ll] = bm;
        }
    }
}

// ---------------- fuse tokens -> x2 (B, 139, 768) ----------------
__global__ __launch_bounds__(256) void fuse_kernel(const float* __restrict__ x1,
                                                   const float* __restrict__ cls,
                                                   const int* __restrict__ idx,
                                                   const int* __restrict__ cmp,
                                                   const int* __restrict__ node,
                                                   float* __restrict__ x2) {
    int mr = blockIdx.x, b = blockIdx.y, tid = threadIdx.x;
    if (mr == 0) {
        for (int c = tid; c < C_; c += 256)
            x2[(size_t)b * NOUT_ * C_ + c] = x1[(size_t)b * N_ * C_ + c];
        return;
    }
    int m = mr - 1;
    __shared__ int nds[COMP_];
    __shared__ int cps[COMP_];
    if (tid < COMP_) {
        nds[tid] = node[b * COMP_ + tid];
        cps[tid] = cmp[b * COMP_ + tid];
    }
    __syncthreads();
    int ti = idx[b * KEEP_ + m];
    float ta = cls[b * 196 + ti];
    float denom = ta;
    for (int l = 0; l < COMP_; l++)
        if (nds[l] == m) denom += cls[b * 196 + cps[l]];
    float a[3];
    const float* xr = x1 + ((size_t)b * N_ + 1 + ti) * C_;
#pragma unroll
    for (int i = 0; i < 3; i++) a[i] = xr[tid + i * 256] * ta;
    for (int l = 0; l < COMP_; l++) {
        if (nds[l] == m) {
            float ca = cls[b * 196 + cps[l]];
            const float* yr = x1 + ((size_t)b * N_ + 1 + cps[l]) * C_;
#pragma unroll
            for (int i = 0; i < 3; i++) a[i] += yr[tid + i * 256] * ca;
        }
    }
    float invd = 1.0f / denom;
#pragma unroll
    for (int i = 0; i < 3; i++)
        x2[((size_t)b * NOUT_ + mr) * C_ + tid + i * 256] = a[i] * invd;
}

extern "C" void kernel_launch(void* const* d_in, const int* in_sizes, int n_in,
                              void* d_out, int out_size, void* d_ws, size_t ws_size,
                              hipStream_t stream) {
    const float* x       = (const float*)d_in[0];
    const float* norm1_w = (const float*)d_in[1];
    const float* norm1_b = (const float*)d_in[2];
    const float* qkv_w   = (const float*)d_in[3];
    const float* proj_w  = (const float*)d_in[4];
    const float* proj_b  = (const float*)d_in[5];
    const float* norm2_w = (const float*)d_in[6];
    const float* norm2_b = (const float*)d_in[7];
    const float* fc1_w   = (const float*)d_in[8];
    const float* fc1_b   = (const float*)d_in[9];
    const float* fc2_w   = (const float*)d_in[10];
    const float* fc2_b   = (const float*)d_in[11];
    float* out = (float*)d_out;

    const int M1 = B_ * N_;      // 25216
    const int M2 = B_ * NOUT_;   // 17792
    const size_t WT_F  = 2359296;
    const size_t C3C   = (size_t)C_ * 3 * C_;
    const size_t CC    = (size_t)C_ * C_;

    const size_t small_f = (size_t)B_ * H_ * N_ + 2u * B_ * 196;
    const size_t small_i = (size_t)B_ * KEEP_ + 2u * B_ * COMP_;
    const size_t x1_f = (size_t)M1 * C_;

    // ---- adaptive tiers (ao planes ALIAS xn planes: xn dead after qkv GEMM) ----
    const int cb_t[4] = {64, 32, 16, 4};
    const int rm_t[4] = {M2, M2, 4864, 320};
    int CB = 4, RMLP = 320;
    size_t scr_f = 0;
    {
        bool ok = false;
        for (int tier = 0; tier < 4; tier++) {
            int cb = cb_t[tier], rm = rm_t[tier];
            size_t cbnc = (size_t)cb * N_ * C_;
            size_t front_f = (C3C + CC) + cbnc + 3 * cbnc;   // 2 fp16 planes each + qkv_c fp32
            size_t mlp_f   = WT_F + (size_t)rm * 1920;
            size_t sf      = front_f > mlp_f ? front_f : mlp_f;
            size_t nd      = (x1_f + sf + small_f) * 4 + small_i * 4;
            if (ws_size >= nd) { CB = cb; RMLP = rm; scr_f = sf; ok = true; break; }
        }
        if (!ok) return;
    }

    float* ws = (float*)d_ws;
    float* x1    = ws;
    float* scr   = x1 + x1_f;
    float* attn0 = scr + scr_f;
    float* cls   = attn0 + (size_t)B_ * H_ * N_;
    float* rn    = cls + B_ * 196;
    int* idxb    = (int*)(rn + B_ * 196);
    int* cmpb    = idxb + B_ * KEEP_;
    int* nodeb   = cmpb + B_ * COMP_;
    float* x2    = out;

    const size_t cbnc = (size_t)CB * N_ * C_;
    us* sb  = (us*)scr;
    us* qw1 = sb;            us* qw2 = qw1 + C3C;
    us* pw1 = qw2 + C3C;     us* pw2 = pw1 + CC;
    us* xn1 = pw2 + CC;      us* xn2 = xn1 + cbnc;
    float* qkv_c = (float*)(xn2 + cbnc);
    us* ao1 = xn1;  us* ao2 = xn2;   // alias: xn dead after qkv GEMM
    us* fc1wt  = (us*)scr;
    us* fc2wt  = fc1wt + (size_t)C_ * HID_;
    us* xn2bf  = fc2wt + (size_t)C_ * HID_;
    us* hmidbf = xn2bf + (size_t)RMLP * C_;

    // ---- front weight prep (scaled fp16 2-plane split, transposed) ----
    wtrans_split2h_kernel<<<dim3(3 * C_ / 32, C_ / 32), 256, 0, stream>>>(qkv_w, qw1, qw2, C_, 3 * C_);
    wtrans_split2h_kernel<<<dim3(C_ / 32, C_ / 32), 256, 0, stream>>>(proj_w, pw1, pw2, C_, C_);

    // ---- front path, chunked over batches (3-product scaled-fp16 MFMA = fp32-grade accuracy) ----
    for (int b0 = 0; b0 < B_; b0 += CB) {
        int cb = (B_ - b0 < CB) ? (B_ - b0) : CB;
        int Mc = cb * N_;
        const float* xch = x + (size_t)b0 * N_ * C_;
        ln_split2h_kernel<<<Mc, 256, 0, stream>>>(xch, norm1_w, norm1_b, xn1, xn2);
        bgemm3h_kernel<false, false><<<dim3(3 * C_ / 128, (Mc + 127) / 128), 256, 0, stream>>>(
            xn1, xn2, qw1, qw2, nullptr, nullptr, qkv_c, Mc, 3 * C_, C_);
        attn12_kernel<<<dim3(H_, cb), 512, 0, stream>>>(qkv_c, ao1, ao2, attn0, b0);
        bgemm3h_kernel<true, true><<<dim3(C_ / 128, (Mc + 127) / 128), 256, 0, stream>>>(
            ao1, ao2, pw1, pw2, proj_b, xch, x1 + (size_t)b0 * N_ * C_, Mc, C_, C_);
    }

    // ---- token selection & fusion ----
    cls_kernel<<<B_, 256, 0, stream>>>(attn0, cls);
    topk_kernel<<<B_, 256, 0, stream>>>(cls, idxb, cmpb);
    rnorm_kernel<<<dim3(196, B_), 256, 0, stream>>>(x1, rn);
    dist4_kernel<<<dim3(B_, 2), 256, 0, stream>>>(x1, rn, idxb, cmpb, nodeb);
    fuse_kernel<<<dim3(NOUT_, B_), 256, 0, stream>>>(x1, cls, idxb, cmpb, nodeb, x2);

    // ---- MLP weight prep (plain bf16) ----
    wtrans_kernel<<<dim3(HID_ / 32, C_ / 32), 256, 0, stream>>>(fc1_w, fc1wt, C_, HID_);
    wtrans_kernel<<<dim3(C_ / 32, HID_ / 32), 256, 0, stream>>>(fc2_w, fc2wt, HID_, C_);

    // ---- MLP, chunked over rows: bf16 MFMA, 256x256 dbuf tile ----
    for (int r0 = 0; r0 < M2; r0 += RMLP) {
        int R = M2 - r0 < RMLP ? M2 - r0 : RMLP;
        ln2bf_kernel<<<R, 256, 0, stream>>>(x2 + (size_t)r0 * C_, norm2_w, norm2_b, xn2bf);
        bgemm_kernel<true, true, false><<<dim3(HID_ / 256, (R + 255) / 256), 512, 0, stream>>>(
            xn2bf, fc1wt, fc1_b, nullptr, hmidbf, R, HID_, C_);
        bgemm_kernel<false, false, true><<<dim3(C_ / 256, (R + 255) / 256), 512, 0, stream>>>(
            hmidbf, fc2wt, fc2_b, x2 + (size_t)r0 * C_, out + (size_t)r0 * C_, R, C_, HID_);
    }
}

// Round 17
// 1302.136 us; speedup vs baseline: 1.1062x; 1.1062x over previous
//
#include <hip/hip_runtime.h>
#include <math.h>

#define B_ 128
#define N_ 197
#define C_ 768
#define H_ 12
#define D_ 64
#define KEEP_ 138
#define COMP_ 58
#define NOUT_ 139
#define HID_ 3072

typedef __attribute__((ext_vector_type(8))) short bf16x8;
typedef __attribute__((ext_vector_type(8))) _Float16 f16x8;
typedef __attribute__((ext_vector_type(4))) float f32x4;
typedef unsigned short us;

__device__ inline us f2bf(float f) {
    unsigned u = __float_as_uint(f);
    unsigned r = (u + 0x7FFFu + ((u >> 16) & 1u)) >> 16;
    return (us)r;
}
__device__ inline float bf2f(us h) { return __uint_as_float(((unsigned)h) << 16); }
__device__ inline void gload_lds16(const void* g, void* l) {
    __builtin_amdgcn_global_load_lds((const __attribute__((address_space(1))) void*)g,
                                     (__attribute__((address_space(3))) void*)l, 16, 0, 0);
}
__device__ inline void split3(float v, us& h1, us& h2, us& h3) {
    h1 = f2bf(v);
    float r1 = v - bf2f(h1);
    h2 = f2bf(r1);
    h3 = f2bf(r1 - bf2f(h2));
}
// fp16 split-2 with scaled residual plane (x ~= h1 + h2*2^-12).
__device__ inline void split2h(float v, us& h1, us& h2) {
    float av = fabsf(v);
    float v1 = (av < 6.103515625e-05f) ? 0.f : v;
    _Float16 a = (_Float16)v1;
    float r = (v - (float)a) * 4096.0f;
    _Float16 b = (_Float16)r;
    h1 = *reinterpret_cast<us*>(&a);
    h2 = *reinterpret_cast<us*>(&b);
}

// Fast GELU (exact-erf form) via Abramowitz-Stegun 7.1.26 (max abs err 1.5e-7);
// bf16-rounded output is bit-identical vs libm erff.
__device__ inline float fast_gelu(float v) {
    float x = v * 0.70710678118654752f;
    float ax = fabsf(x);
    float t = __frcp_rn(__fmaf_rn(0.3275911f, ax, 1.0f));
    float p = __fmaf_rn(1.061405429f, t, -1.453152027f);
    p = __fmaf_rn(p, t, 1.421413741f);
    p = __fmaf_rn(p, t, -0.284496736f);
    p = __fmaf_rn(p, t, 0.254829592f);
    p = p * t;
    float e = __expf(-x * x);
    float erfa = __fmaf_rn(-p, e, 1.0f);
    float er = (x < 0.f) ? -erfa : erfa;
    return 0.5f * v * (1.0f + er);
}

// XCD-aware bijective grid swizzle (T1, m204 formula). Pure index permutation ->
// bitwise-identical results. Round-14 verified (-41 us via qkv/proj L2 locality).
__device__ inline void xcd_swizzle(int GX, int GY, int& bx, int& by) {
    int nwg = GX * GY;
    int orig = by * GX + bx;
    int q = nwg >> 3, r = nwg & 7;
    int xcd = orig & 7, idx = orig >> 3;
    int wgid = (xcd < r ? xcd * (q + 1) : r * (q + 1) + (xcd - r) * q) + idx;
    bx = wgid % GX;
    by = wgid / GX;
}

// counted-vmcnt barrier discipline (T4): never drain vmcnt to 0 in the main loop.
#define WAITV(n) asm volatile("s_waitcnt vmcnt(" #n ")" ::: "memory")
#define RBAR __builtin_amdgcn_s_barrier()

// ---------------- LayerNorm1 -> 2-plane scaled fp16 split ----------------
__global__ __launch_bounds__(256) void ln_split2h_kernel(const float* __restrict__ x,
                                                         const float* __restrict__ w,
                                                         const float* __restrict__ bias,
                                                         us* __restrict__ y1,
                                                         us* __restrict__ y2) {
    int row = blockIdx.x;
    const float* xr = x + (size_t)row * C_;
    int tid = threadIdx.x;
    float v[3];
    float s = 0.f, sq = 0.f;
#pragma unroll
    for (int i = 0; i < 3; i++) {
        v[i] = xr[tid + i * 256];
        s += v[i];
        sq += v[i] * v[i];
    }
    __shared__ float s1[256], s2[256];
    s1[tid] = s; s2[tid] = sq;
    __syncthreads();
    for (int o = 128; o > 0; o >>= 1) {
        if (tid < o) { s1[tid] += s1[tid + o]; s2[tid] += s2[tid + o]; }
        __syncthreads();
    }
    float mean = s1[0] * (1.0f / C_);
    float var = s2[0] * (1.0f / C_) - mean * mean;
    float rstd = rsqrtf(var + 1e-5f);
#pragma unroll
    for (int i = 0; i < 3; i++) {
        int c = tid + i * 256;
        float y = (v[i] - mean) * rstd * w[c] + bias[c];
        us h1, h2;
        split2h(y, h1, h2);
        size_t o = (size_t)row * C_ + c;
        y1[o] = h1; y2[o] = h2;
    }
}

// ---------------- LayerNorm -> bf16 output (MLP) ----------------
__global__ __launch_bounds__(256) void ln2bf_kernel(const float* __restrict__ x,
                                                    const float* __restrict__ w,
                                                    const float* __restrict__ bias,
                                                    us* __restrict__ y) {
    int row = blockIdx.x;
    const float* xr = x + (size_t)row * C_;
    us* yr = y + (size_t)row * C_;
    int tid = threadIdx.x;
    float v[3];
    float s = 0.f, sq = 0.f;
#pragma unroll
    for (int i = 0; i < 3; i++) {
        v[i] = xr[tid + i * 256];
        s += v[i];
        sq += v[i] * v[i];
    }
    __shared__ float s1[256], s2[256];
    s1[tid] = s; s2[tid] = sq;
    __syncthreads();
    for (int o = 128; o > 0; o >>= 1) {
        if (tid < o) { s1[tid] += s1[tid + o]; s2[tid] += s2[tid + o]; }
        __syncthreads();
    }
    float mean = s1[0] * (1.0f / C_);
    float var = s2[0] * (1.0f / C_) - mean * mean;
    float rstd = rsqrtf(var + 1e-5f);
#pragma unroll
    for (int i = 0; i < 3; i++) {
        int c = tid + i * 256;
        yr[c] = f2bf((v[i] - mean) * rstd * w[c] + bias[c]);
    }
}

// ---------------- weight transpose: in[K][N] fp32 -> out[N][K] bf16 (MLP) ----------------
__global__ __launch_bounds__(256) void wtrans_kernel(const float* __restrict__ in,
                                                     us* __restrict__ out,
                                                     int K, int N) {
    __shared__ float T[32][33];
    int n0 = blockIdx.x * 32, k0 = blockIdx.y * 32;
    int tx = threadIdx.x & 31, ty = threadIdx.x >> 5;
    for (int i = 0; i < 32; i += 8)
        T[ty + i][tx] = in[(size_t)(k0 + ty + i) * N + n0 + tx];
    __syncthreads();
    for (int i = 0; i < 32; i += 8)
        out[(size_t)(n0 + ty + i) * K + k0 + tx] = f2bf(T[tx][ty + i]);
}

// ---------------- weight transpose split2h: in[K][N] fp32 -> 2x [N][K] fp16 ----------------
__global__ __launch_bounds__(256) void wtrans_split2h_kernel(const float* __restrict__ in,
                                                             us* __restrict__ o1,
                                                             us* __restrict__ o2,
                                                             int K, int N) {
    __shared__ float T[32][33];
    int n0 = blockIdx.x * 32, k0 = blockIdx.y * 32;
    int tx = threadIdx.x & 31, ty = threadIdx.x >> 5;
    for (int i = 0; i < 32; i += 8)
        T[ty + i][tx] = in[(size_t)(k0 + ty + i) * N + n0 + tx];
    __syncthreads();
    for (int i = 0; i < 32; i += 8) {
        us h1, h2;
        split2h(T[tx][ty + i], h1, h2);
        size_t o = (size_t)(n0 + ty + i) * K + k0 + tx;
        o1[o] = h1; o2[o] = h2;
    }
}

// ---------------- split-2 scaled-fp16 MFMA GEMM (front), 3 products ----------------
// Round-6 verified: 2 blocks/CU, BK=64, zero bank conflicts. Round-14: + XCD swizzle.
template <bool BIAS, bool RES>
__global__ __launch_bounds__(256, 2) void bgemm3h_kernel(const us* __restrict__ A1,
                                                         const us* __restrict__ A2,
                                                         const us* __restrict__ B1,
                                                         const us* __restrict__ B2,
                                                         const float* __restrict__ bias,
                                                         const float* __restrict__ res,
                                                         float* __restrict__ Cm,
                                                         int M, int N, int K) {
    __shared__ short As[2][128 * 64];
    __shared__ short Bs[2][128 * 64];
    int tid = threadIdx.x;
    int lane = tid & 63, wid = tid >> 6;
    int wr = wid >> 1, wc = wid & 1;
    int lr = lane & 15, g = lane >> 4;
    int bx = blockIdx.x, by = blockIdx.y;
    xcd_swizzle(gridDim.x, gridDim.y, bx, by);
    int brow = by * 128, bcol = bx * 128;

    f32x4 acc0[4][4] = {};
    f32x4 acc1[4][4] = {};

    for (int k0 = 0; k0 < K; k0 += 64) {
#pragma unroll
        for (int v = 0; v < 4; v++) {
            int rowb = v * 32 + wid * 8;           // wave-uniform 8-row group
            int r = rowb + (lane >> 3);
            int slot = lane & 7;
            int chunk = slot ^ (r & 7);
            int garow = brow + r; if (garow >= M) garow = M - 1;
            int gbrow = bcol + r;
            gload_lds16(A1 + (size_t)garow * K + k0 + chunk * 8, &As[0][rowb * 64]);
            gload_lds16(A2 + (size_t)garow * K + k0 + chunk * 8, &As[1][rowb * 64]);
            gload_lds16(B1 + (size_t)gbrow * K + k0 + chunk * 8, &Bs[0][rowb * 64]);
            gload_lds16(B2 + (size_t)gbrow * K + k0 + chunk * 8, &Bs[1][rowb * 64]);
        }
        __syncthreads();
#pragma unroll
        for (int kk = 0; kk < 2; kk++) {
            f16x8 af[2][4], bfr[2][4];
#pragma unroll
            for (int fi = 0; fi < 4; fi++) {
                int ra = wr * 64 + fi * 16 + lr;
                int sla = (kk * 4 + g) ^ (ra & 7);
                int rb = wc * 64 + fi * 16 + lr;
                int slb = (kk * 4 + g) ^ (rb & 7);
#pragma unroll
                for (int s = 0; s < 2; s++) {
                    af[s][fi] = *reinterpret_cast<const f16x8*>(&As[s][ra * 64 + sla * 8]);
                    bfr[s][fi] = *reinterpret_cast<const f16x8*>(&Bs[s][rb * 64 + slb * 8]);
                }
            }
#pragma unroll
            for (int fi = 0; fi < 4; fi++)
#pragma unroll
                for (int fj = 0; fj < 4; fj++) {
                    acc0[fi][fj] = __builtin_amdgcn_mfma_f32_16x16x32_f16(af[0][fi], bfr[0][fj], acc0[fi][fj], 0, 0, 0);
                    acc1[fi][fj] = __builtin_amdgcn_mfma_f32_16x16x32_f16(af[0][fi], bfr[1][fj], acc1[fi][fj], 0, 0, 0);
                    acc1[fi][fj] = __builtin_amdgcn_mfma_f32_16x16x32_f16(af[1][fi], bfr[0][fj], acc1[fi][fj], 0, 0, 0);
                }
        }
        __syncthreads();
    }
#pragma unroll
    for (int fi = 0; fi < 4; fi++) {
#pragma unroll
        for (int fj = 0; fj < 4; fj++) {
            int col = bcol + wc * 64 + fj * 16 + lr;
            float bv = BIAS ? bias[col] : 0.f;
#pragma unroll
            for (int i = 0; i < 4; i++) {
                int r = brow + wr * 64 + fi * 16 + g * 4 + i;
                if (r < M) {
                    float vv = acc0[fi][fj][i] + acc1[fi][fj][i] * (1.0f / 4096.0f) + bv;
                    if (RES) vv += res[(size_t)r * N + col];
                    Cm[(size_t)r * N + col] = vv;
                }
            }
        }
    }
}

// ---------------- bf16 MFMA GEMM (MLP): round-11 verified body + XCD swizzle ----------------
// BK=64 single-buffer, 8-row-group staging, (r&7) XOR swizzle (0 bank conflicts),
// 32 MFMA + 8 ds_read_b128 per barrier-pair, __launch_bounds__(256, 4):
// 32 KB LDS -> up to 4 blocks/CU. Round-15's 256^2 dbuf variant regressed
// (1 block/CU, MfmaUtil 12.6%) -- residency x payload is maximized here.
template <bool GELU_, bool OUTBF, bool RES>
__global__ __launch_bounds__(256, 4) void bgemm_kernel(const us* __restrict__ A,
                                                       const us* __restrict__ Bt,
                                                       const float* __restrict__ bias,
                                                       const float* __restrict__ res,
                                                       void* __restrict__ Cout,
                                                       int M, int N, int K) {
    __shared__ short As[128 * 64];
    __shared__ short Bs[128 * 64];
    int tid = threadIdx.x;
    int lane = tid & 63, wid = tid >> 6;
    int wr = wid >> 1, wc = wid & 1;
    int lr = lane & 15, g = lane >> 4;
    int bx = blockIdx.x, by = blockIdx.y;
    xcd_swizzle(gridDim.x, gridDim.y, bx, by);
    int brow = by * 128, bcol = bx * 128;

    f32x4 acc[4][4] = {};

    for (int k0 = 0; k0 < K; k0 += 64) {
#pragma unroll
        for (int v = 0; v < 4; v++) {
            int rowb = v * 32 + wid * 8;
            int r = rowb + (lane >> 3);
            int slot = lane & 7;
            int chunk = slot ^ (r & 7);
            int garow = brow + r; if (garow >= M) garow = M - 1;
            gload_lds16(A + (size_t)garow * K + k0 + chunk * 8, &As[rowb * 64]);
            gload_lds16(Bt + (size_t)(bcol + r) * K + k0 + chunk * 8, &Bs[rowb * 64]);
        }
        __syncthreads();
#pragma unroll
        for (int kk = 0; kk < 2; kk++) {
            bf16x8 af[4], bfr[4];
#pragma unroll
            for (int fi = 0; fi < 4; fi++) {
                int ra = wr * 64 + fi * 16 + lr;
                int sla = (kk * 4 + g) ^ (ra & 7);
                int rb = wc * 64 + fi * 16 + lr;
                int slb = (kk * 4 + g) ^ (rb & 7);
                af[fi] = *reinterpret_cast<const bf16x8*>(&As[ra * 64 + sla * 8]);
                bfr[fi] = *reinterpret_cast<const bf16x8*>(&Bs[rb * 64 + slb * 8]);
            }
#pragma unroll
            for (int fi = 0; fi < 4; fi++)
#pragma unroll
                for (int fj = 0; fj < 4; fj++)
                    acc[fi][fj] = __builtin_amdgcn_mfma_f32_16x16x32_bf16(af[fi], bfr[fj], acc[fi][fj], 0, 0, 0);
        }
        __syncthreads();
    }
#pragma unroll
    for (int fi = 0; fi < 4; fi++) {
#pragma unroll
        for (int fj = 0; fj < 4; fj++) {
            int col = bcol + wc * 64 + fj * 16 + lr;
            float bv = bias[col];
#pragma unroll
            for (int i = 0; i < 4; i++) {
                int r = brow + wr * 64 + fi * 16 + g * 4 + i;
                if (r < M) {
                    float vv = acc[fi][fj][i] + bv;
                    if (GELU_) vv = fast_gelu(vv);
                    if (OUTBF) {
                        ((us*)Cout)[(size_t)r * N + col] = f2bf(vv);
                    } else {
                        if (RES) vv += res[(size_t)r * N + col];
                        ((float*)Cout)[(size_t)r * N + col] = vv;
                    }
                }
            }
        }
    }
}

// ---------------- attention v12: scaled-fp16 split-2 QK^T + padded Pscr (round-12 verified) ----------------
__global__ __launch_bounds__(512, 1) void attn12_kernel(const float* __restrict__ qkv,
                                                        us* __restrict__ ao1,
                                                        us* __restrict__ ao2,
                                                        float* __restrict__ attn0,
                                                        int b0) {
    int hh = blockIdx.x, b = blockIdx.y;
    int tid = threadIdx.x, lane = tid & 63, wv = tid >> 6;
    int lr = lane & 15, g = lane >> 4;
    __shared__ short Ks[2][208 * 64];
    __shared__ short Vt[2][64 * 224];
    __shared__ unsigned Pscr[8][16 * 36];
    const size_t base = (size_t)b * N_ * 3 * C_ + (size_t)hh * D_;

    for (int i = tid; i < 208 * 8; i += 512) {
        int k = i >> 3, oct = i & 7;
        int d0 = (oct ^ (k & 7)) * 8;
        float tv[8];
        if (k < N_) {
            const float4* kp = reinterpret_cast<const float4*>(qkv + base + (size_t)k * 3 * C_ + C_ + d0);
            float4 aa = kp[0], bb = kp[1];
            tv[0] = aa.x; tv[1] = aa.y; tv[2] = aa.z; tv[3] = aa.w;
            tv[4] = bb.x; tv[5] = bb.y; tv[6] = bb.z; tv[7] = bb.w;
        } else {
#pragma unroll
            for (int e = 0; e < 8; e++) tv[e] = 0.f;
        }
        bf16x8 h1v, h2v;
#pragma unroll
        for (int e = 0; e < 8; e++) {
            us ha, hb;
            split2h(tv[e], ha, hb);
            h1v[e] = (short)ha; h2v[e] = (short)hb;
        }
        int di = k * 64 + oct * 8;
        *reinterpret_cast<bf16x8*>(&Ks[0][di]) = h1v;
        *reinterpret_cast<bf16x8*>(&Ks[1][di]) = h2v;
    }
    {
        int d = tid & 63, jb = tid >> 6;
        for (int it = 0; it < 28; it++) {
            int k = it * 8 + jb;
            float vv = (k < N_) ? qkv[base + (size_t)k * 3 * C_ + 2 * C_ + d] : 0.f;
            us p1 = f2bf(vv);
            us p2 = f2bf(vv - bf2f(p1));
            int idx = d * 224 + (((k >> 3) ^ (d & 3)) * 8) + (k & 7);
            Vt[0][idx] = (short)p1;
            Vt[1][idx] = (short)p2;
        }
    }
    __syncthreads();

#pragma unroll
    for (int chunk = 0; chunk < 2; chunk++) {
        int qbase = chunk * 128 + wv * 16;
        f16x8 qf1[2], qf2[2];
        int qrow = qbase + lr;
#pragma unroll
        for (int kk = 0; kk < 2; kk++) {
            float qv[8];
            if (qrow < N_) {
                const float4* qp = reinterpret_cast<const float4*>(qkv + base + (size_t)qrow * 3 * C_ + kk * 32 + g * 8);
                float4 aa = qp[0], bb = qp[1];
                qv[0] = aa.x; qv[1] = aa.y; qv[2] = aa.z; qv[3] = aa.w;
                qv[4] = bb.x; qv[5] = bb.y; qv[6] = bb.z; qv[7] = bb.w;
            } else {
#pragma unroll
                for (int e = 0; e < 8; e++) qv[e] = 0.f;
            }
#pragma unroll
            for (int e = 0; e < 8; e++) {
                us ha, hb;
                split2h(qv[e], ha, hb);
                qf1[kk][e] = *reinterpret_cast<_Float16*>(&ha);
                qf2[kk][e] = *reinterpret_cast<_Float16*>(&hb);
            }
        }
        f32x4 sacc[13] = {};
        f32x4 sacc1[13] = {};
#pragma unroll
        for (int kt = 0; kt < 13; kt++) {
#pragma unroll
            for (int kk = 0; kk < 2; kk++) {
                int row = kt * 16 + lr;
                int sl = ((kk * 4 + g) ^ (row & 7)) * 8;
                const f16x8 b1 = *reinterpret_cast<const f16x8*>(&Ks[0][row * 64 + sl]);
                const f16x8 b2 = *reinterpret_cast<const f16x8*>(&Ks[1][row * 64 + sl]);
                sacc[kt]  = __builtin_amdgcn_mfma_f32_16x16x32_f16(qf1[kk], b1, sacc[kt], 0, 0, 0);
                sacc1[kt] = __builtin_amdgcn_mfma_f32_16x16x32_f16(qf1[kk], b2, sacc1[kt], 0, 0, 0);
                sacc1[kt] = __builtin_amdgcn_mfma_f32_16x16x32_f16(qf2[kk], b1, sacc1[kt], 0, 0, 0);
            }
        }
#pragma unroll
        for (int kt = 0; kt < 13; kt++)
#pragma unroll
            for (int i = 0; i < 4; i++)
                sacc[kt][i] += sacc1[kt][i] * (1.0f / 4096.0f);
#pragma unroll
        for (int i = 0; i < 4; i++) {
            float m = -1e30f;
#pragma unroll
            for (int kt = 0; kt < 13; kt++) {
                int k = kt * 16 + lr;
                float lgv = (k < N_) ? sacc[kt][i] * 0.125f : -1e30f;
                sacc[kt][i] = lgv;
                m = fmaxf(m, lgv);
            }
            m = fmaxf(m, __shfl_xor(m, 1, 64));
            m = fmaxf(m, __shfl_xor(m, 2, 64));
            m = fmaxf(m, __shfl_xor(m, 4, 64));
            m = fmaxf(m, __shfl_xor(m, 8, 64));
            float se = 0.f;
#pragma unroll
            for (int kt = 0; kt < 13; kt++) {
                int k = kt * 16 + lr;
                float e = (k < N_) ? expf(sacc[kt][i] - m) : 0.f;
                sacc[kt][i] = e;
                se += e;
            }
            se += __shfl_xor(se, 1, 64);
            se += __shfl_xor(se, 2, 64);
            se += __shfl_xor(se, 4, 64);
            se += __shfl_xor(se, 8, 64);
            float inv = 1.0f / se;
#pragma unroll
            for (int kt = 0; kt < 13; kt++) sacc[kt][i] *= inv;
        }
        if (chunk == 0 && wv == 0 && g == 0) {
#pragma unroll
            for (int kt = 0; kt < 13; kt++) {
                int k = kt * 16 + lr;
                if (k < N_) attn0[((size_t)(b0 + b) * H_ + hh) * N_ + k] = sacc[kt][0];
            }
        }
        f32x4 oacc[4] = {};
#pragma unroll
        for (int sect = 0; sect < 7; sect++) {
#pragma unroll
            for (int t = 0; t < 2; t++) {
                int kt = sect * 2 + t;
#pragma unroll
                for (int i = 0; i < 4; i++) {
                    float p = (kt < 13) ? sacc[kt][i] : 0.f;
                    us h1 = f2bf(p);
                    us h2 = f2bf(p - bf2f(h1));
                    Pscr[wv][(g * 4 + i) * 36 + t * 16 + lr] = (unsigned)h1 | ((unsigned)h2 << 16);
                }
            }
            uint4 u0 = *reinterpret_cast<const uint4*>(&Pscr[wv][lr * 36 + g * 8]);
            uint4 u1 = *reinterpret_cast<const uint4*>(&Pscr[wv][lr * 36 + g * 8 + 4]);
            unsigned uu[8] = {u0.x, u0.y, u0.z, u0.w, u1.x, u1.y, u1.z, u1.w};
            bf16x8 pa1, pa2;
#pragma unroll
            for (int e = 0; e < 8; e++) {
                pa1[e] = (short)(uu[e] & 0xffffu);
                pa2[e] = (short)(uu[e] >> 16);
            }
#pragma unroll
            for (int dt = 0; dt < 4; dt++) {
                int row = dt * 16 + lr;
                int cc = sect * 4 + g;
                int idx = row * 224 + ((cc ^ (row & 3)) * 8);
                const bf16x8 v1 = *reinterpret_cast<const bf16x8*>(&Vt[0][idx]);
                const bf16x8 v2 = *reinterpret_cast<const bf16x8*>(&Vt[1][idx]);
                oacc[dt] = __builtin_amdgcn_mfma_f32_16x16x32_bf16(pa1, v1, oacc[dt], 0, 0, 0);
                oacc[dt] = __builtin_amdgcn_mfma_f32_16x16x32_bf16(pa1, v2, oacc[dt], 0, 0, 0);
                oacc[dt] = __builtin_amdgcn_mfma_f32_16x16x32_bf16(pa2, v1, oacc[dt], 0, 0, 0);
            }
        }
#pragma unroll
        for (int dt = 0; dt < 4; dt++) {
#pragma unroll
            for (int i = 0; i < 4; i++) {
                int q = qbase + g * 4 + i;
                if (q < N_) {
                    int d = dt * 16 + lr;
                    size_t oi = ((size_t)(b * N_ + q)) * C_ + (size_t)hh * D_ + d;
                    us h1, h2;
                    split2h(oacc[dt][i], h1, h2);
                    ao1[oi] = h1; ao2[oi] = h2;
                }
            }
        }
    }
}

// ---------------- cls_attn ----------------
__global__ __launch_bounds__(256) void cls_kernel(const float* __restrict__ attn0,
                                                  float* __restrict__ cls) {
    int b = blockIdx.x, tid = threadIdx.x;
    if (tid < N_ - 1) {
        float s = 0.f;
        for (int hh = 0; hh < H_; hh++) s += attn0[((size_t)b * H_ + hh) * N_ + 1 + tid];
        cls[b * (N_ - 1) + tid] = s * (1.0f / H_);
    }
}

// ---------------- top-k + complement ----------------
__global__ __launch_bounds__(256) void topk_kernel(const float* __restrict__ cls,
                                                   int* __restrict__ idx,
                                                   int* __restrict__ cmp) {
    int b = blockIdx.x, tid = threadIdx.x;
    __shared__ float vals[196];
    __shared__ int rk[196];
    if (tid < 196) vals[tid] = cls[b * 196 + tid];
    __syncthreads();
    if (tid < 196) {
        float v = vals[tid];
        int r = 0;
        for (int j = 0; j < 196; j++) {
            float u = vals[j];
            r += (u > v) || (u == v && j < tid);
        }
        rk[tid] = r;
    }
    __syncthreads();
    if (tid < 196) {
        int r = rk[tid];
        if (r < KEEP_) {
            idx[b * KEEP_ + r] = tid;
        } else {
            int pos = 0;
            for (int j = 0; j < tid; j++) pos += (rk[j] >= KEEP_);
            cmp[b * COMP_ + pos] = tid;
        }
    }
}

// ---------------- reciprocal L2 norms ----------------
__global__ __launch_bounds__(256) void rnorm_kernel(const float* __restrict__ x1,
                                                    float* __restrict__ rn) {
    int i = blockIdx.x, b = blockIdx.y, tid = threadIdx.x;
    const float* xr = x1 + ((size_t)b * N_ + 1 + i) * C_;
    float sq = 0.f;
#pragma unroll
    for (int k = 0; k < 3; k++) {
        float v = xr[tid + k * 256];
        sq += v * v;
    }
    __shared__ float s2[256];
    s2[tid] = sq;
    __syncthreads();
    for (int o = 128; o > 0; o >>= 1) {
        if (tid < o) s2[tid] += s2[tid + o];
        __syncthreads();
    }
    if (tid == 0) rn[b * 196 + i] = rsqrtf(s2[0]);
}

// ---------------- distance v4: k-contiguous b128 LDS layout (round-13 verified) ----------------
__global__ __launch_bounds__(256, 3) void dist4_kernel(const float* __restrict__ x1,
                                                       const float* __restrict__ rn,
                                                       const int* __restrict__ idx,
                                                       const int* __restrict__ cmp,
                                                       int* __restrict__ node) {
    int b = blockIdx.x, half = blockIdx.y;
    int l0 = half * 29;
    int tid = threadIdx.x;
    __shared__ __align__(16) float As2[32][64];
    __shared__ __align__(16) float Bs2[138][64];
    __shared__ int cpl[29];
    __shared__ int til[KEEP_];
    __shared__ float rnt[KEEP_];
    if (tid < 29) cpl[tid] = cmp[b * COMP_ + l0 + tid];
    if (tid < KEEP_) {
        int t = idx[b * KEEP_ + tid];
        til[tid] = t;
        rnt[tid] = rn[b * 196 + t];
    }
    __syncthreads();
    int tr = tid >> 5, tc = tid & 31;
    int mb[5], mm[5];
#pragma unroll
    for (int j = 0; j < 5; j++) {
        int m = tc * 5 + j;
        int mc = (m < KEEP_) ? m : (KEEP_ - 1);
        mb[j] = mc * 64;
        mm[j] = mc & 15;
    }
    float acc[4][5] = {};
    for (int k0 = 0; k0 < C_; k0 += 64) {
        for (int ii = tid; ii < 29 * 16; ii += 256) {
            int l = ii >> 4, kc = ii & 15;
            *reinterpret_cast<float4*>(&As2[l][kc * 4]) =
                *reinterpret_cast<const float4*>(&x1[((size_t)b * N_ + 1 + cpl[l]) * C_ + k0 + kc * 4]);
        }
        for (int ii = tid; ii < KEEP_ * 16; ii += 256) {
            int m = ii >> 4, kc = ii & 15;
            *reinterpret_cast<float4*>(&Bs2[m][(kc ^ (m & 15)) * 4]) =
                *reinterpret_cast<const float4*>(&x1[((size_t)b * N_ + 1 + til[m]) * C_ + k0 + kc * 4]);
        }
        __syncthreads();
#pragma unroll 4
        for (int kc = 0; kc < 16; kc++) {
            float4 a4[4], b4[5];
#pragma unroll
            for (int i = 0; i < 4; i++)
                a4[i] = *reinterpret_cast<const float4*>(&As2[tr * 4 + i][kc * 4]);
#pragma unroll
            for (int j = 0; j < 5; j++)
                b4[j] = *reinterpret_cast<const float4*>(&Bs2[0][0] + mb[j] + ((kc ^ mm[j]) << 2));
#pragma unroll
            for (int i = 0; i < 4; i++)
#pragma unroll
                for (int j = 0; j < 5; j++) {
                    acc[i][j] += a4[i].x * b4[j].x;
                    acc[i][j] += a4[i].y * b4[j].y;
                    acc[i][j] += a4[i].z * b4[j].z;
                    acc[i][j] += a4[i].w * b4[j].w;
                }
        }
        __syncthreads();
    }
#pragma unroll
    for (int i = 0; i < 4; i++) {
        int ll = tr * 4 + i;
        if (ll < 29) {
            float best = -3.0e38f;
            int bm = 0x7fffffff;
#pragma unroll
            for (int j = 0; j < 5; j++) {
                int m = tc * 5 + j;
                if (m < KEEP_) {
                    float dv = acc[i][j] * rnt[m];
                    if (dv > best) { best = dv; bm = m; }
                }
            }
            for (int o = 1; o < 32; o <<= 1) {
                float ov = __shfl_xor(best, o, 64);
                int oi = __shfl_xor(bm, o, 64);
                if (ov > best || (ov == best && oi < bm)) { best = ov; bm = oi; }
            }
            if (tc == 0) node[b * COMP_ + l0 + ll] = bm;
        }
    }
}

// ---------------- fuse tokens -> x2 (B, 139, 768) ----------------
__global__ __launch_bounds__(256) void fuse_kernel(const float* __restrict__ x1,
                                                   const float* __restrict__ cls,
                                                   const int* __restrict__ idx,
                                                   const int* __restrict__ cmp,
                                                   const int* __restrict__ node,
                                                   float* __restrict__ x2) {
    int mr = blockIdx.x, b = blockIdx.y, tid = threadIdx.x;
    if (mr == 0) {
        for (int c = tid; c < C_; c += 256)
            x2[(size_t)b * NOUT_ * C_ + c] = x1[(size_t)b * N_ * C_ + c];
        return;
    }
    int m = mr - 1;
    __shared__ int nds[COMP_];
    __shared__ int cps[COMP_];
    if (tid < COMP_) {
        nds[tid] = node[b * COMP_ + tid];
        cps[tid] = cmp[b * COMP_ + tid];
    }
    __syncthreads();
    int ti = idx[b * KEEP_ + m];
    float ta = cls[b * 196 + ti];
    float denom = ta;
    for (int l = 0; l < COMP_; l++)
        if (nds[l] == m) denom += cls[b * 196 + cps[l]];
    float a[3];
    const float* xr = x1 + ((size_t)b * N_ + 1 + ti) * C_;
#pragma unroll
    for (int i = 0; i < 3; i++) a[i] = xr[tid + i * 256] * ta;
    for (int l = 0; l < COMP_; l++) {
        if (nds[l] == m) {
            float ca = cls[b * 196 + cps[l]];
            const float* yr = x1 + ((size_t)b * N_ + 1 + cps[l]) * C_;
#pragma unroll
            for (int i = 0; i < 3; i++) a[i] += yr[tid + i * 256] * ca;
        }
    }
    float invd = 1.0f / denom;
#pragma unroll
    for (int i = 0; i < 3; i++)
        x2[((size_t)b * NOUT_ + mr) * C_ + tid + i * 256] = a[i] * invd;
}

extern "C" void kernel_launch(void* const* d_in, const int* in_sizes, int n_in,
                              void* d_out, int out_size, void* d_ws, size_t ws_size,
                              hipStream_t stream) {
    const float* x       = (const float*)d_in[0];
    const float* norm1_w = (const float*)d_in[1];
    const float* norm1_b = (const float*)d_in[2];
    const float* qkv_w   = (const float*)d_in[3];
    const float* proj_w  = (const float*)d_in[4];
    const float* proj_b  = (const float*)d_in[5];
    const float* norm2_w = (const float*)d_in[6];
    const float* norm2_b = (const float*)d_in[7];
    const float* fc1_w   = (const float*)d_in[8];
    const float* fc1_b   = (const float*)d_in[9];
    const float* fc2_w   = (const float*)d_in[10];
    const float* fc2_b   = (const float*)d_in[11];
    float* out = (float*)d_out;

    const int M1 = B_ * N_;      // 25216
    const int M2 = B_ * NOUT_;   // 17792
    const size_t WT_F  = 2359296;
    const size_t C3C   = (size_t)C_ * 3 * C_;
    const size_t CC    = (size_t)C_ * C_;

    const size_t small_f = (size_t)B_ * H_ * N_ + 2u * B_ * 196;
    const size_t small_i = (size_t)B_ * KEEP_ + 2u * B_ * COMP_;
    const size_t x1_f = (size_t)M1 * C_;

    // ---- adaptive tiers (ao planes ALIAS xn planes: xn dead after qkv GEMM) ----
    const int cb_t[4] = {64, 32, 16, 4};
    const int rm_t[4] = {M2, M2, 4864, 320};
    int CB = 4, RMLP = 320;
    size_t scr_f = 0;
    {
        bool ok = false;
        for (int tier = 0; tier < 4; tier++) {
            int cb = cb_t[tier], rm = rm_t[tier];
            size_t cbnc = (size_t)cb * N_ * C_;
            size_t front_f = (C3C + CC) + cbnc + 3 * cbnc;   // 2 fp16 planes each + qkv_c fp32
            size_t mlp_f   = WT_F + (size_t)rm * 1920;
            size_t sf      = front_f > mlp_f ? front_f : mlp_f;
            size_t nd      = (x1_f + sf + small_f) * 4 + small_i * 4;
            if (ws_size >= nd) { CB = cb; RMLP = rm; scr_f = sf; ok = true; break; }
        }
        if (!ok) return;
    }

    float* ws = (float*)d_ws;
    float* x1    = ws;
    float* scr   = x1 + x1_f;
    float* attn0 = scr + scr_f;
    float* cls   = attn0 + (size_t)B_ * H_ * N_;
    float* rn    = cls + B_ * 196;
    int* idxb    = (int*)(rn + B_ * 196);
    int* cmpb    = idxb + B_ * KEEP_;
    int* nodeb   = cmpb + B_ * COMP_;
    float* x2    = out;

    const size_t cbnc = (size_t)CB * N_ * C_;
    us* sb  = (us*)scr;
    us* qw1 = sb;            us* qw2 = qw1 + C3C;
    us* pw1 = qw2 + C3C;     us* pw2 = pw1 + CC;
    us* xn1 = pw2 + CC;      us* xn2 = xn1 + cbnc;
    float* qkv_c = (float*)(xn2 + cbnc);
    us* ao1 = xn1;  us* ao2 = xn2;   // alias: xn dead after qkv GEMM
    us* fc1wt  = (us*)scr;
    us* fc2wt  = fc1wt + (size_t)C_ * HID_;
    us* xn2bf  = fc2wt + (size_t)C_ * HID_;
    us* hmidbf = xn2bf + (size_t)RMLP * C_;

    // ---- front weight prep (scaled fp16 2-plane split, transposed) ----
    wtrans_split2h_kernel<<<dim3(3 * C_ / 32, C_ / 32), 256, 0, stream>>>(qkv_w, qw1, qw2, C_, 3 * C_);
    wtrans_split2h_kernel<<<dim3(C_ / 32, C_ / 32), 256, 0, stream>>>(proj_w, pw1, pw2, C_, C_);

    // ---- front path, chunked over batches (3-product scaled-fp16 MFMA = fp32-grade accuracy) ----
    for (int b0 = 0; b0 < B_; b0 += CB) {
        int cb = (B_ - b0 < CB) ? (B_ - b0) : CB;
        int Mc = cb * N_;
        const float* xch = x + (size_t)b0 * N_ * C_;
        ln_split2h_kernel<<<Mc, 256, 0, stream>>>(xch, norm1_w, norm1_b, xn1, xn2);
        bgemm3h_kernel<false, false><<<dim3(3 * C_ / 128, (Mc + 127) / 128), 256, 0, stream>>>(
            xn1, xn2, qw1, qw2, nullptr, nullptr, qkv_c, Mc, 3 * C_, C_);
        attn12_kernel<<<dim3(H_, cb), 512, 0, stream>>>(qkv_c, ao1, ao2, attn0, b0);
        bgemm3h_kernel<true, true><<<dim3(C_ / 128, (Mc + 127) / 128), 256, 0, stream>>>(
            ao1, ao2, pw1, pw2, proj_b, xch, x1 + (size_t)b0 * N_ * C_, Mc, C_, C_);
    }

    // ---- token selection & fusion ----
    cls_kernel<<<B_, 256, 0, stream>>>(attn0, cls);
    topk_kernel<<<B_, 256, 0, stream>>>(cls, idxb, cmpb);
    rnorm_kernel<<<dim3(196, B_), 256, 0, stream>>>(x1, rn);
    dist4_kernel<<<dim3(B_, 2), 256, 0, stream>>>(x1, rn, idxb, cmpb, nodeb);
    fuse_kernel<<<dim3(NOUT_, B_), 256, 0, stream>>>(x1, cls, idxb, cmpb, nodeb, x2);

    // ---- MLP weight prep (plain bf16) ----
    wtrans_kernel<<<dim3(HID_ / 32, C_ / 32), 256, 0, stream>>>(fc1_w, fc1wt, C_, HID_);
    wtrans_kernel<<<dim3(C_ / 32, HID_ / 32), 256, 0, stream>>>(fc2_w, fc2wt, HID_, C_);

    // ---- MLP, chunked over rows: bf16 MFMA, BK=64 front-shape, 4 blocks/CU ----
    for (int r0 = 0; r0 < M2; r0 += RMLP) {
        int R = M2 - r0 < RMLP ? M2 - r0 : RMLP;
        ln2bf_kernel<<<R, 256, 0, stream>>>(x2 + (size_t)r0 * C_, norm2_w, norm2_b, xn2bf);
        bgemm_kernel<true, true, false><<<dim3(HID_ / 128, (R + 127) / 128), 256, 0, stream>>>(
            xn2bf, fc1wt, fc1_b, nullptr, hmidbf, R, HID_, C_);
        bgemm_kernel<false, false, true><<<dim3(C_ / 128, (R + 127) / 128), 256, 0, stream>>>(
            hmidbf, fc2wt, fc2_b, x2 + (size_t)r0 * C_, out + (size_t)r0 * C_, R, C_, HID_);
    }
}